// Round 1
// baseline (351.844 us; speedup 1.0000x reference)
//
#include <hip/hip_runtime.h>
#include <hip/hip_bf16.h>

// Problem constants
constexpr int N  = 32;
constexpr int C  = 16;   // in channels
constexpr int H  = 256;
constexpr int W  = 256;
constexpr int CO = 16;   // out channels
constexpr int KS = 3;
constexpr int OH = 254;
constexpr int OW = 254;

constexpr float SUBV = 0.7f;   // SUB1 + SUB2

// Tiling
constexpr int TW = 64;         // output tile width  (per block)
constexpr int TH = 16;         // output tile height (per block)
constexpr int CICHUNK = 4;     // input channels staged per LDS pass
constexpr int IN_W = TW + 4;   // 68 floats = 17 float4 (need TW+2 halo; +2 pad for alignment)
constexpr int IN_H = TH + 2;   // 18 rows
constexpr int QUADS_PER_ROW = IN_W / 4;          // 17
constexpr int STAGE_QUADS = CICHUNK * IN_H * QUADS_PER_ROW;  // 1224

// ---------------------------------------------------------------------------
// Kernel 1: reorder weights OIHW -> [ci][ky][kx][co] (contiguous over co) and
// append (bias - 0.7). Lives in d_ws. Re-run every launch (d_ws re-poisoned).
// ---------------------------------------------------------------------------
__global__ void reorder_weights(const float* __restrict__ w,
                                const float* __restrict__ b,
                                float* __restrict__ wr) {
    const int t = threadIdx.x;
    for (int i = t; i < C * KS * KS * CO; i += blockDim.x) {
        const int co   = i % CO;
        const int rest = i / CO;          // ci*9 + ky*3 + kx
        const int kx   = rest % 3;
        const int ky   = (rest / 3) % 3;
        const int ci   = rest / 9;
        wr[i] = w[((co * C + ci) * KS + ky) * KS + kx];
    }
    if (t < CO) wr[C * KS * KS * CO + t] = b[t] - SUBV;
}

// ---------------------------------------------------------------------------
// Kernel 2: fused conv3x3 + bias + sub + mish.
// Block: 256 threads. Thread t: column group col = t&15 (4 consecutive x),
// row py = t>>4. Each thread computes 4 px * 16 co accumulators.
// ---------------------------------------------------------------------------
__launch_bounds__(256, 4)
__global__ void conv_mish(const float* __restrict__ x,
                          const float* __restrict__ wr,
                          float* __restrict__ out) {
    __shared__ float lds[CICHUNK * IN_H * IN_W];

    const int tid = threadIdx.x;
    const int x0  = blockIdx.x * TW;   // output-tile x origin (also input x origin)
    const int oy0 = blockIdx.y * TH;   // output-tile y origin (also input y origin)
    const int n   = blockIdx.z;

    const int col = tid & 15;
    const int py  = tid >> 4;
    const int px0 = col * 4;

    float acc[4][CO];
#pragma unroll
    for (int p = 0; p < 4; ++p)
#pragma unroll
        for (int co = 0; co < CO; ++co) acc[p][co] = 0.0f;

    for (int cc = 0; cc < C; cc += CICHUNK) {
        if (cc) __syncthreads();   // protect LDS reuse across chunks

        // ---- stage CICHUNK input channels into LDS (float4 coalesced) ----
        const float* src = x + ((size_t)(n * C + cc) * H) * W;
        for (int q = tid; q < STAGE_QUADS; q += 256) {
            const int ciq  = q / (IN_H * QUADS_PER_ROW);
            int rem        = q - ciq * (IN_H * QUADS_PER_ROW);
            const int row  = rem / QUADS_PER_ROW;
            const int quad = rem - row * QUADS_PER_ROW;
            int iy = oy0 + row;      if (iy > H - 1) iy = H - 1;     // clamp: garbage rows never used by valid outputs
            int ix = x0 + quad * 4;  if (ix > W - 4) ix = W - 4;     // clamp: garbage cols never used by valid outputs
            const float4 v = *(const float4*)(src + ((size_t)ciq * H + iy) * W + ix);
            *(float4*)(&lds[(ciq * IN_H + row) * IN_W + quad * 4]) = v;
        }
        __syncthreads();

        // ---- compute over the staged chunk ----
#pragma unroll
        for (int ci = 0; ci < CICHUNK; ++ci) {
            // 3 input rows x 6 floats needed by this thread's 4 px and 3x3 window
            float in[3][6];
#pragma unroll
            for (int r = 0; r < 3; ++r) {
                const float* p = &lds[(ci * IN_H + py + r) * IN_W + px0];
                const float4 a = *(const float4*)p;        // 16B aligned
                const float2 bl = *(const float2*)(p + 4); // 8B aligned
                in[r][0] = a.x; in[r][1] = a.y; in[r][2] = a.z; in[r][3] = a.w;
                in[r][4] = bl.x; in[r][5] = bl.y;
            }
            const float* wp = wr + (cc + ci) * 9 * CO;   // [ky][kx][co], uniform -> s_load
#pragma unroll
            for (int ky = 0; ky < 3; ++ky) {
#pragma unroll
                for (int kx = 0; kx < 3; ++kx) {
#pragma unroll
                    for (int co = 0; co < CO; ++co) {
                        const float wv = wp[(ky * 3 + kx) * CO + co];
#pragma unroll
                        for (int p = 0; p < 4; ++p)
                            acc[p][co] = fmaf(in[ky][kx + p], wv, acc[p][co]);
                    }
                }
            }
        }
    }

    // ---- epilogue: bias - 0.7, mish, predicated stores ----
    const int oy = oy0 + py;
    if (oy < OH) {
#pragma unroll
        for (int co = 0; co < CO; ++co) {
            const float bias = wr[C * KS * KS * CO + co];   // uniform -> s_load
            float* orow = out + ((size_t)(n * CO + co) * OH + oy) * OW;
#pragma unroll
            for (int p = 0; p < 4; ++p) {
                const int ox = x0 + px0 + p;
                if (ox < OW) {
                    const float v  = acc[p][co] + bias;
                    // mish(v) = v * tanh(softplus(v)) = v * (z^2-1)/(z^2+1), z = 1+e^v
                    const float vc = fminf(v, 15.0f);       // overflow guard; tanh saturates to 1
                    const float e  = __expf(vc);
                    const float z  = 1.0f + e;
                    const float z2 = z * z;
                    const float t  = __fdividef(z2 - 1.0f, z2 + 1.0f);
                    orow[ox] = v * t;
                }
            }
        }
    }
}

extern "C" void kernel_launch(void* const* d_in, const int* in_sizes, int n_in,
                              void* d_out, int out_size, void* d_ws, size_t ws_size,
                              hipStream_t stream) {
    const float* x = (const float*)d_in[0];
    const float* w = (const float*)d_in[1];
    const float* b = (const float*)d_in[2];
    float* out = (float*)d_out;
    float* wr  = (float*)d_ws;   // needs (2304+16)*4 = 9280 bytes

    hipLaunchKernelGGL(reorder_weights, dim3(1), dim3(256), 0, stream, w, b, wr);

    dim3 grid((OW + TW - 1) / TW, (OH + TH - 1) / TH, N);   // 4 x 16 x 32
    hipLaunchKernelGGL(conv_mish, grid, dim3(256), 0, stream, x, wr, out);
}

// Round 2
// 337.323 us; speedup vs baseline: 1.0430x; 1.0430x over previous
//
#include <hip/hip_runtime.h>
#include <hip/hip_bf16.h>

// Problem constants
constexpr int N  = 32;
constexpr int C  = 16;   // in channels
constexpr int H  = 256;
constexpr int W  = 256;
constexpr int CO = 16;   // out channels
constexpr int KS = 3;
constexpr int OH = 254;
constexpr int OW = 254;

constexpr float SUBV = 0.7f;   // SUB1 + SUB2

// Tiling
constexpr int TW = 64;         // output tile width  (per block)
constexpr int TH = 16;         // output tile height (per block)
constexpr int CICHUNK = 4;     // input channels staged per LDS pass
constexpr int IN_W = TW + 4;   // 68 floats (need TW+2 halo; +2 pad keeps float4 alignment)
constexpr int IN_H = TH + 2;   // 18 rows
constexpr int QUADS_PER_ROW = IN_W / 4;          // 17
constexpr int STAGE_QUADS = CICHUNK * IN_H * QUADS_PER_ROW;  // 1224

constexpr int BLK = 512;       // 8 waves; co split across tid>>8

// ---------------------------------------------------------------------------
// Kernel 1: reorder weights OIHW -> [ci][ky][kx][co] (contiguous over co) and
// append (bias - 0.7). Lives in d_ws (re-poisoned each launch, so re-run).
// ---------------------------------------------------------------------------
__global__ void reorder_weights(const float* __restrict__ w,
                                const float* __restrict__ b,
                                float* __restrict__ wr) {
    const int t = threadIdx.x;
    for (int i = t; i < C * KS * KS * CO; i += blockDim.x) {
        const int co   = i % CO;
        const int rest = i / CO;          // ci*9 + ky*3 + kx
        const int kx   = rest % 3;
        const int ky   = (rest / 3) % 3;
        const int ci   = rest / 9;
        wr[i] = w[((co * C + ci) * KS + ky) * KS + kx];
    }
    if (t < CO) wr[C * KS * KS * CO + t] = b[t] - SUBV;
}

// ---------------------------------------------------------------------------
// Kernel 2: fused conv3x3 + bias + sub + mish.
// Block: 512 threads. col = t&15 (4 consecutive x), py = (t>>4)&15 (row),
// coh = t>>8 (which half of the 16 output channels).
// Each thread: 4 px * 8 co = 32 accumulators (fits VGPRs -> no spills).
// ---------------------------------------------------------------------------
__launch_bounds__(BLK, 4)
__global__ void conv_mish(const float* __restrict__ x,
                          const float* __restrict__ wr,
                          float* __restrict__ out) {
    __shared__ float lds[CICHUNK * IN_H * IN_W];   // 19584 B

    const int tid = threadIdx.x;
    const int x0  = blockIdx.x * TW;
    const int oy0 = blockIdx.y * TH;
    const int n   = blockIdx.z;

    const int col = tid & 15;
    const int py  = (tid >> 4) & 15;
    // wave-uniform by construction (512 = 8 waves; lanes of a wave share tid>>8).
    // readfirstlane forces the compiler to treat it as scalar -> weight reads stay s_load.
    const int coh = __builtin_amdgcn_readfirstlane(tid >> 8);
    const int px0 = col * 4;

    float acc[4][8];
#pragma unroll
    for (int p = 0; p < 4; ++p)
#pragma unroll
        for (int co = 0; co < 8; ++co) acc[p][co] = 0.0f;

#pragma unroll 1
    for (int cc = 0; cc < C; cc += CICHUNK) {
        if (cc) __syncthreads();   // protect LDS reuse across chunks

        // ---- stage CICHUNK input channels into LDS (float4 coalesced) ----
        const float* src = x + ((size_t)(n * C + cc) * H) * W;
        for (int q = tid; q < STAGE_QUADS; q += BLK) {
            const int ciq  = q / (IN_H * QUADS_PER_ROW);
            int rem        = q - ciq * (IN_H * QUADS_PER_ROW);
            const int row  = rem / QUADS_PER_ROW;
            const int quad = rem - row * QUADS_PER_ROW;
            int iy = oy0 + row;      if (iy > H - 1) iy = H - 1;     // clamped cells never feed stored outputs
            int ix = x0 + quad * 4;  if (ix > W - 4) ix = W - 4;
            const float4 v = *(const float4*)(src + ((size_t)ciq * H + iy) * W + ix);
            *(float4*)(&lds[(ciq * IN_H + row) * IN_W + quad * 4]) = v;
        }
        __syncthreads();

        // ---- compute over the staged chunk ----
#pragma unroll
        for (int ci = 0; ci < CICHUNK; ++ci) {
            float in[3][6];
#pragma unroll
            for (int r = 0; r < 3; ++r) {
                const float* p = &lds[(ci * IN_H + py + r) * IN_W + px0];
                const float4 a  = *(const float4*)p;        // 16B aligned
                const float2 bl = *(const float2*)(p + 4);  // 8B aligned
                in[r][0] = a.x; in[r][1] = a.y; in[r][2] = a.z; in[r][3] = a.w;
                in[r][4] = bl.x; in[r][5] = bl.y;
            }
            // [ky][kx][co] layout; uniform address -> s_load
            const float* wp = wr + (cc + ci) * 9 * CO + coh * 8;
#pragma unroll
            for (int ky = 0; ky < 3; ++ky) {
#pragma unroll
                for (int kx = 0; kx < 3; ++kx) {
#pragma unroll
                    for (int co = 0; co < 8; ++co) {
                        const float wv = wp[(ky * 3 + kx) * CO + co];
#pragma unroll
                        for (int p = 0; p < 4; ++p)
                            acc[p][co] = fmaf(in[ky][kx + p], wv, acc[p][co]);
                    }
                }
            }
        }
    }

    // ---- epilogue: bias - 0.7, mish, vectorized stores ----
    const int oy = oy0 + py;
    if (oy < OH) {
        const int ox = x0 + px0;
#pragma unroll
        for (int co = 0; co < 8; ++co) {
            const int gco = coh * 8 + co;
            const float bias = wr[C * KS * KS * CO + gco];   // uniform -> s_load
            float* orow = out + ((size_t)(n * CO + gco) * OH + oy) * OW;
            float r[4];
#pragma unroll
            for (int p = 0; p < 4; ++p) {
                const float v  = acc[p][co] + bias;
                // mish(v) = v * tanh(softplus(v)) = v * (z^2-1)/(z^2+1), z = 1+e^v
                const float vc = fminf(v, 15.0f);            // tanh saturated beyond this
                const float e  = __expf(vc);
                const float z  = 1.0f + e;
                const float z2 = z * z;
                r[p] = v * __fdividef(z2 - 1.0f, z2 + 1.0f);
            }
            if (ox + 3 < OW) {
                *(float4*)(orow + ox) = make_float4(r[0], r[1], r[2], r[3]);
            } else {
#pragma unroll
                for (int p = 0; p < 4; ++p)
                    if (ox + p < OW) orow[ox + p] = r[p];
            }
        }
    }
}

extern "C" void kernel_launch(void* const* d_in, const int* in_sizes, int n_in,
                              void* d_out, int out_size, void* d_ws, size_t ws_size,
                              hipStream_t stream) {
    const float* x = (const float*)d_in[0];
    const float* w = (const float*)d_in[1];
    const float* b = (const float*)d_in[2];
    float* out = (float*)d_out;
    float* wr  = (float*)d_ws;   // (2304+16)*4 = 9280 bytes

    hipLaunchKernelGGL(reorder_weights, dim3(1), dim3(256), 0, stream, w, b, wr);

    dim3 grid((OW + TW - 1) / TW, (OH + TH - 1) / TH, N);   // 4 x 16 x 32
    hipLaunchKernelGGL(conv_mish, grid, dim3(BLK), 0, stream, x, wr, out);
}

// Round 3
// 286.805 us; speedup vs baseline: 1.2268x; 1.1761x over previous
//
#include <hip/hip_runtime.h>
#include <hip/hip_bf16.h>

// Problem constants
constexpr int N   = 32;
constexpr int C   = 16;    // in channels
constexpr int H   = 256;
constexpr int W   = 256;
constexpr int CO  = 16;    // out channels
constexpr int OH  = 254;
constexpr int OW  = 254;
constexpr float SUBV = 0.7f;   // SUB1 + SUB2

// GEMM-view: k = (ky*3+kx)*16 + ci, K=144 padded to 160 (5 chunks of 32)
constexpr int KPAD = 160;

// Tiling
constexpr int TY    = 14;          // output rows per block
constexpr int TIN_Y = TY + 2;      // 16 staged input rows
constexpr int TX    = 64;          // output px per block (4 waves x 16)
constexpr int TIN_X = TX + 2;      // 66
constexpr int XS    = 24;          // per-x LDS stride in ushorts (48 B: 32 B data + 16 B pad, breaks bank conflicts)
constexpr int ROW_US = TIN_X * XS; // 1584 ushorts (3168 B) per staged row

using short8  = __attribute__((ext_vector_type(8))) short;
using floatx4 = __attribute__((ext_vector_type(4))) float;

__device__ inline uint bf16u(float f) {           // RNE float->bf16 bits (inputs are finite)
    uint u = __builtin_bit_cast(uint, f);
    u += 0x7fffu + ((u >> 16) & 1u);
    return u >> 16;
}

// ---------------------------------------------------------------------------
// Kernel 1: weights -> bf16, k-reordered A-matrix [co][KPAD]; k<144 real, rest 0.
// Bias (fp32, -0.7 folded) appended at ushort offset 2560 (byte 5120).
// ---------------------------------------------------------------------------
__global__ void reorder_weights(const float* __restrict__ w,
                                const float* __restrict__ b,
                                ushort* __restrict__ wr) {
    const int t = threadIdx.x;
    for (int i = t; i < CO * KPAD; i += 256) {
        const int co = i / KPAD;
        const int k  = i - co * KPAD;
        ushort v = 0;
        if (k < 144) {
            const int pair = k >> 4;          // ky*3+kx, 0..8
            const int ci   = k & 15;
            const int ky   = pair / 3;
            const int kx   = pair - 3 * ky;
            v = (ushort)bf16u(w[((co * C + ci) * 3 + ky) * 3 + kx]);
        }
        wr[i] = v;
    }
    if (t < CO) ((float*)(wr + CO * KPAD))[t] = b[t] - SUBV;
}

// ---------------------------------------------------------------------------
// Kernel 2: implicit-GEMM conv3x3 via bf16 MFMA 16x16x32, fused bias+mish.
// Block 256 thr = 4 waves. Wave w owns the 16-px column [x0+16w, +16).
// LDS: input tile [16 rows][66 x][16 ci] bf16, x-stride 48 B.
// ---------------------------------------------------------------------------
__launch_bounds__(256, 3)
__global__ void conv_mfma(const float* __restrict__ x,
                          const ushort* __restrict__ wr,
                          float* __restrict__ out) {
    __shared__ ushort lds[TIN_Y * ROW_US];   // 50688 B

    const int tid  = threadIdx.x;
    const int lane = tid & 63;
    const int wave = tid >> 6;
    const int quad = lane >> 4;
    const int n    = lane & 15;              // pixel within 16-px tile / co for A load

    const int x0 = blockIdx.x * TX;
    const int y0 = blockIdx.y * TY;
    const int ni = blockIdx.z;

    // ---- per-lane A fragments (weights), loaded from global (L2-hot) ----
    short8 afrag[5];
    {
        const ushort* wbase = wr + n * KPAD + quad * 8;   // A[m=co=n][k=32c+8*quad+j]
        #pragma unroll
        for (int c = 0; c < 5; ++c)
            afrag[c] = *(const short8*)(wbase + c * 32);
    }
    // bias for this lane's 4 co values (co = quad*4 + j)
    float bias_j[4];
    {
        const float* bp = (const float*)(wr + CO * KPAD);
        const float4 bv = *(const float4*)(bp + quad * 4);
        bias_j[0] = bv.x; bias_j[1] = bv.y; bias_j[2] = bv.z; bias_j[3] = bv.w;
    }
    // B-fragment LDS offsets (ushorts) per k-chunk
    int boff[5];
    #pragma unroll
    for (int c = 0; c < 5; ++c) {
        int pair = 2 * c + (quad >> 1);
        if (pair > 8) pair = 8;              // pad chunk reads real data x zero weights
        const int ky = pair / 3;
        const int kx = pair - 3 * ky;
        boff[c] = ky * ROW_US + (n + kx) * XS + (quad & 1) * 8;
    }
    // output store bases (co = quad*4 + j)
    size_t obase[4];
    const int oxv = x0 + wave * 16 + n;
    const bool oxok = oxv < OW;
    #pragma unroll
    for (int j = 0; j < 4; ++j)
        obase[j] = ((size_t)(ni * CO + quad * 4 + j)) * OH * OW + oxv;

    // ---- stage input tile: global fp32 [ci][y][x] -> LDS bf16 [y][x][ci] ----
    {
        const float* xs = x + (size_t)ni * C * H * W;
        for (int sp = tid; sp < (TIN_Y * TIN_X) / 2; sp += 256) {   // 528 site-pairs
            const int s  = sp * 2;
            const int yy = s / TIN_X;
            const int xx = s - yy * TIN_X;                           // even; pair stays in row (66 even)
            const int iy  = (y0 + yy < H - 1) ? (y0 + yy) : (H - 1); // clamped cells feed only masked outputs
            const int ixp = (x0 + xx < W - 2) ? (x0 + xx) : (W - 2);
            const float* src = xs + (size_t)iy * W + ixp;
            uint a[8], b[8];
            #pragma unroll
            for (int ci = 0; ci < C; ci += 2) {
                const float2 p0 = *(const float2*)(src + (size_t)ci * H * W);
                const float2 p1 = *(const float2*)(src + (size_t)(ci + 1) * H * W);
                a[ci >> 1] = bf16u(p0.x) | (bf16u(p1.x) << 16);
                b[ci >> 1] = bf16u(p0.y) | (bf16u(p1.y) << 16);
            }
            ushort* d0 = &lds[(yy * TIN_X + xx) * XS];
            ((uint4*)d0)[0] = make_uint4(a[0], a[1], a[2], a[3]);
            ((uint4*)d0)[1] = make_uint4(a[4], a[5], a[6], a[7]);
            ushort* d1 = d0 + XS;
            ((uint4*)d1)[0] = make_uint4(b[0], b[1], b[2], b[3]);
            ((uint4*)d1)[1] = make_uint4(b[4], b[5], b[6], b[7]);
        }
    }
    __syncthreads();

    // ---- K-loop per output-row pair: 10 ds_read_b128 + 10 MFMA ----
    const ushort* wcol = lds + wave * 16 * XS;
    #pragma unroll 1
    for (int r = 0; r < TY; r += 2) {
        floatx4 acc0 = {0.f, 0.f, 0.f, 0.f};
        floatx4 acc1 = {0.f, 0.f, 0.f, 0.f};
        const ushort* b0 = wcol + r * ROW_US;
        const ushort* b1 = b0 + ROW_US;
        #pragma unroll
        for (int c = 0; c < 5; ++c) {
            const short8 f0 = *(const short8*)(b0 + boff[c]);
            const short8 f1 = *(const short8*)(b1 + boff[c]);
            acc0 = __builtin_amdgcn_mfma_f32_16x16x32_bf16(afrag[c], f0, acc0, 0, 0, 0);
            acc1 = __builtin_amdgcn_mfma_f32_16x16x32_bf16(afrag[c], f1, acc1, 0, 0, 0);
        }
        // epilogue: D col = lane&15 = pix, row = quad*4+reg = co
        #pragma unroll
        for (int rr = 0; rr < 2; ++rr) {
            const int oy = y0 + r + rr;
            if (oy < OH && oxok) {
                const floatx4 av = rr ? acc1 : acc0;
                #pragma unroll
                for (int j = 0; j < 4; ++j) {
                    const float v  = av[j] + bias_j[j];
                    const float vc = fminf(v, 15.0f);        // tanh saturated beyond
                    const float e  = __expf(vc);
                    const float z  = 1.0f + e;
                    const float z2 = z * z;
                    const float t  = __fdividef(z2 - 1.0f, z2 + 1.0f);
                    out[obase[j] + (size_t)oy * OW] = v * t; // mish
                }
            }
        }
    }
}

extern "C" void kernel_launch(void* const* d_in, const int* in_sizes, int n_in,
                              void* d_out, int out_size, void* d_ws, size_t ws_size,
                              hipStream_t stream) {
    const float* x = (const float*)d_in[0];
    const float* w = (const float*)d_in[1];
    const float* b = (const float*)d_in[2];
    float* out = (float*)d_out;
    ushort* wr = (ushort*)d_ws;   // 2560*2 + 16*4 = 5184 bytes

    hipLaunchKernelGGL(reorder_weights, dim3(1), dim3(256), 0, stream, w, b, wr);

    dim3 grid(OW / TX + 1, (OH + TY - 1) / TY, N);   // 4 x 19 x 32
    hipLaunchKernelGGL(conv_mfma, grid, dim3(256), 0, stream, x, wr, out);
}